// Round 20
// baseline (44.161 us; speedup 1.0000x reference)
//
#include <hip/hip_runtime.h>
#include <hip/hip_bf16.h>
#include <math.h>

#define BB 4
#define SS 2048
#define EE 1024
#define HH 64
#define BS (BB*SS)   // 8192 rows total

typedef __attribute__((ext_vector_type(8))) short bf16x8;
typedef __attribute__((ext_vector_type(4))) float f32x4;

static __device__ __forceinline__ unsigned int f2b(float f) {
  __hip_bfloat16 h = __float2bfloat16(f);
  unsigned short u;
  __builtin_memcpy(&u, &h, 2);
  return (unsigned int)u;
}

// ---------------------------------------------------------------------------
// Kernel 0: W transpose+convert.  wt[n][e] bf16, n = which*64 + h.
// Wq pre-scaled by (1/32)*log2e (exp2-domain scores). R18 verbatim.
// ---------------------------------------------------------------------------
__global__ __launch_bounds__(256) void wt_prep(const float* __restrict__ Wq,
                                               const float* __restrict__ Wk,
                                               const float* __restrict__ Wv,
                                               unsigned short* __restrict__ wt) {
  __shared__ float tile[64 * 69];
  const int blk = blockIdx.x;
  const int w = blk >> 4;
  const int et = blk & 15;
  const int t = threadIdx.x;
  const float* __restrict__ W = (w == 0) ? Wq : ((w == 1) ? Wk : Wv);

#pragma unroll
  for (int i = 0; i < 4; ++i) {
    const int idx = t + i * 256;
    const int row = idx >> 4;
    const int f4 = idx & 15;
    const float4 v = *(const float4*)(W + ((size_t)(et * 64 + row)) * 64 + f4 * 4);
    tile[row * 69 + f4 * 4 + 0] = v.x;
    tile[row * 69 + f4 * 4 + 1] = v.y;
    tile[row * 69 + f4 * 4 + 2] = v.z;
    tile[row * 69 + f4 * 4 + 3] = v.w;
  }
  __syncthreads();

  const float scale = (w == 0) ? 0.03125f * 1.4426950408889634f : 1.0f;
  const int h = t >> 2;
  const int eg = (t & 3) * 16;
  unsigned int o[8];
#pragma unroll
  for (int i = 0; i < 8; ++i) {
    const float a = tile[(eg + 2 * i + 0) * 69 + h] * scale;
    const float b = tile[(eg + 2 * i + 1) * 69 + h] * scale;
    o[i] = f2b(a) | (f2b(b) << 16);
  }
  unsigned short* dst = wt + ((size_t)(w * 64 + h)) * 1024 + et * 64 + eg;
  uint4 lo4; lo4.x = o[0]; lo4.y = o[1]; lo4.z = o[2]; lo4.w = o[3];
  uint4 hi4; hi4.x = o[4]; hi4.y = o[5]; hi4.z = o[6]; hi4.w = o[7];
  *(uint4*)dst = lo4;
  *(uint4*)(dst + 8) = hi4;
}

// ---------------------------------------------------------------------------
// Kernel A: QKV projection — R18 verbatim (depth-3 x prefetch; measured win).
// ---------------------------------------------------------------------------
__global__ __launch_bounds__(512) void qkv_mfma(const float* __restrict__ x,
                                                const unsigned short* __restrict__ wt,
                                                unsigned short* __restrict__ qb,
                                                unsigned short* __restrict__ kbuf,
                                                unsigned short* __restrict__ vtb) {
  __shared__ char smem[57344];   // xs[2][4096] | ws[2][24576]
  const int t = threadIdx.x;
  const int blk = blockIdx.x;
  const int lane = t & 63;
  const int wv = t >> 6;
  const int wm = wv >> 2;        // 0..1
  const int wn = wv & 3;         // 0..3
  const int lo = lane & 15, hi = lane >> 4;

  const int xrow = t >> 4;       // 0..31
  const int xf4 = t & 15;
  const int wr0 = t >> 3;        // 0..63
  const int wc = t & 7;

  const float* __restrict__ xsrc = x + ((size_t)blk * 32 + xrow) * 1024 + xf4 * 4;
  const unsigned short* __restrict__ wsrc = wt + (size_t)wr0 * 1024 + wc * 8;

  float4 xpre[3];
  bf16x8 wrg[3];
  f32x4 acc[3] = {};

#define LOADX(slot, kt) xpre[slot] = *(const float4*)(xsrc + (kt) * 64)
#define LOADW(kt)                                                     \
  do {                                                                \
    wrg[0] = *(const bf16x8*)(wsrc + (kt) * 64);                      \
    wrg[1] = *(const bf16x8*)(wsrc + 64 * 1024 + (kt) * 64);          \
    wrg[2] = *(const bf16x8*)(wsrc + 128 * 1024 + (kt) * 64);         \
  } while (0)

#define WRITEX(buf, slot)                                                    \
  do {                                                                       \
    uint2 pv;                                                                \
    pv.x = f2b(xpre[slot].x) | (f2b(xpre[slot].y) << 16);                    \
    pv.y = f2b(xpre[slot].z) | (f2b(xpre[slot].w) << 16);                    \
    *(uint2*)&smem[(buf) * 4096 + xrow * 128 +                               \
                   ((xf4 * 8) ^ ((xrow & 7) << 4))] = pv;                    \
  } while (0)

#define WRITEW(buf)                                                          \
  do {                                                                       \
    char* wb = &smem[8192 + (buf) * 24576];                                  \
    const int sw = (wc * 16) ^ ((wr0 & 7) << 4);                             \
    *(bf16x8*)&wb[(wr0 + 0) * 128 + sw] = wrg[0];                            \
    *(bf16x8*)&wb[(wr0 + 64) * 128 + sw] = wrg[1];                           \
    *(bf16x8*)&wb[(wr0 + 128) * 128 + sw] = wrg[2];                          \
  } while (0)

  LOADX(0, 0); LOADX(1, 1); LOADX(2, 2);
  LOADW(0);
  WRITEX(0, 0);
  WRITEW(0);
  __syncthreads();

  const int arow = wm * 16 + lo;
  const int aswz = (arow & 7) << 4;

#pragma unroll
  for (int kt = 0; kt < 16; ++kt) {
    const int cur = kt & 1;
    if (kt + 1 < 16) LOADW(kt + 1);
    if (kt + 3 < 16) LOADX(kt % 3, kt + 3);

    const char* xb = &smem[cur * 4096];
    const char* wb = &smem[8192 + cur * 24576];
    const bf16x8 a0 = *(const bf16x8*)&xb[arow * 128 + ((hi * 16) ^ aswz)];
    const bf16x8 a1 = *(const bf16x8*)&xb[arow * 128 + ((64 + hi * 16) ^ aswz)];
#pragma unroll
    for (int nf = 0; nf < 3; ++nf) {
      const int brow = wn * 48 + nf * 16 + lo;
      const int bswz = (brow & 7) << 4;
      const bf16x8 b0 = *(const bf16x8*)&wb[brow * 128 + ((hi * 16) ^ bswz)];
      const bf16x8 b1 = *(const bf16x8*)&wb[brow * 128 + ((64 + hi * 16) ^ bswz)];
      acc[nf] = __builtin_amdgcn_mfma_f32_16x16x32_bf16(a0, b0, acc[nf], 0, 0, 0);
      acc[nf] = __builtin_amdgcn_mfma_f32_16x16x32_bf16(a1, b1, acc[nf], 0, 0, 0);
    }

    if (kt + 1 < 16) {
      WRITEX(cur ^ 1, (kt + 1) % 3);
      WRITEW(cur ^ 1);
    }
    __syncthreads();
  }

  const int m0 = blk * 32 + wm * 16 + hi * 4;
#pragma unroll
  for (int nf = 0; nf < 3; ++nf) {
    const int nb = wn * 48 + nf * 16;
    const int which = nb >> 6;
    const int h = (nb & 63) + lo;
#pragma unroll
    for (int r = 0; r < 4; ++r) {
      const int row = m0 + r;
      const unsigned short v = (unsigned short)f2b(acc[nf][r]);
      if (which == 0) qb[(size_t)row * 64 + h] = v;
      else if (which == 1) kbuf[(size_t)row * 64 + h] = v;
      else vtb[((size_t)(row >> 11) * 64 + h) * 2048 + (row & 2047)] = v;
    }
  }
#undef LOADX
#undef LOADW
#undef WRITEX
#undef WRITEW
}

// ---------------------------------------------------------------------------
// Kernel B: causal flash attention — R18/R15/R11 structure with ONE change:
// the V-frag hoist is issued BEFORE the QK^T MFMA cluster (V independent of
// K/Q), so 8 more loads are in flight while QK^T stalls on K-load deps.
// Adjacent 2-q-group + snake, 8-way split-K, setprio, exp2 softmax,
// exact skip-rescale. No K prefetch (measured negative twice).
// ---------------------------------------------------------------------------
__global__ __launch_bounds__(512) void attn_mfma(const unsigned short* __restrict__ qb,
                                                 const unsigned short* __restrict__ kbuf,
                                                 const unsigned short* __restrict__ vt,
                                                 float* __restrict__ out) {
  __shared__ __align__(16) float sacc[8][16][64];  // 32 KB (reused per group)
  __shared__ float sml[2][8][16];

  const int t = threadIdx.x;
  const int lane = t & 63;
  const int w = t >> 6;            // 0..7 (split-K wave)
  const int lo = lane & 15, hi = lane >> 4;
  const int hi4 = hi * 4;

  const int blk = blockIdx.x;      // 0..255
  const int batch = blk & 3;
  const int tt = blk >> 2;         // 0..63
  const int qt = (tt & 1) ? (63 - (tt >> 1)) : (tt >> 1);  // snake
  const int q0 = qt * 32;

  const unsigned short* Qb = qb   + (size_t)batch * SS * 64;
  const unsigned short* Kb = kbuf + (size_t)batch * SS * 64;
  const unsigned short* Vt = vt   + (size_t)batch * 64 * SS;

  const int qA = q0 + lo;
  const int qBr = q0 + 16 + lo;

  const bf16x8 qf0a = *(const bf16x8*)(Qb + (size_t)qA * 64 + hi * 8);
  const bf16x8 qf1a = *(const bf16x8*)(Qb + (size_t)qA * 64 + 32 + hi * 8);
  const bf16x8 qf0b = *(const bf16x8*)(Qb + (size_t)qBr * 64 + hi * 8);
  const bf16x8 qf1b = *(const bf16x8*)(Qb + (size_t)qBr * 64 + 32 + hi * 8);

  f32x4 accA[4] = {}, accB[4] = {};
  float mA = -1e30f, lA = 0.f, mB = -1e30f, lB = 0.f;

  const int kend = q0 + 32;
  for (int kbase = w * 64; kbase < kend; kbase += 512) {
    // ---- V-frag hoist FIRST: independent loads in flight before QK^T ----
    bf16x8 va[2][4];
#pragma unroll
    for (int kc = 0; kc < 2; ++kc)
#pragma unroll
      for (int j = 0; j < 4; ++j)
        va[kc][j] = *(const bf16x8*)(Vt + (size_t)(j * 16 + lo) * SS +
                                     kbase + kc * 32 + hi * 8);

    // ---- QK^T for both groups (K frags shared) ----
    f32x4 sA[4], sB[4];
    __builtin_amdgcn_s_setprio(1);
#pragma unroll
    for (int j0 = 0; j0 < 4; ++j0) {
      const unsigned short* Krow = Kb + (size_t)(kbase + j0 * 16 + lo) * 64 + hi * 8;
      const bf16x8 ka = *(const bf16x8*)(Krow);
      const bf16x8 kb2 = *(const bf16x8*)(Krow + 32);
      f32x4 ca = {}, cb = {};
      ca = __builtin_amdgcn_mfma_f32_16x16x32_bf16(ka, qf0a, ca, 0, 0, 0);
      ca = __builtin_amdgcn_mfma_f32_16x16x32_bf16(kb2, qf1a, ca, 0, 0, 0);
      cb = __builtin_amdgcn_mfma_f32_16x16x32_bf16(ka, qf0b, cb, 0, 0, 0);
      cb = __builtin_amdgcn_mfma_f32_16x16x32_bf16(kb2, qf1b, cb, 0, 0, 0);
      sA[j0] = ca; sB[j0] = cb;
    }
    __builtin_amdgcn_s_setprio(0);

    // ---- causal mask ----
    if (kbase + 64 > q0) {
#pragma unroll
      for (int j0 = 0; j0 < 4; ++j0)
#pragma unroll
        for (int r = 0; r < 4; ++r) {
          const int key = kbase + j0 * 16 + hi4 + r;
          sA[j0][r] = (key > qA) ? -1e30f : sA[j0][r];
          sB[j0][r] = (key > qBr) ? -1e30f : sB[j0][r];
        }
    }

    // ---- softmax group A ----
    unsigned int WA[4][2], WB[4][2];
    {
      float mx = fmaxf(fmaxf(sA[0][0], sA[0][1]), fmaxf(sA[0][2], sA[0][3]));
      mx = fmaxf(mx, fmaxf(fmaxf(sA[1][0], sA[1][1]), fmaxf(sA[1][2], sA[1][3])));
      mx = fmaxf(mx, fmaxf(fmaxf(sA[2][0], sA[2][1]), fmaxf(sA[2][2], sA[2][3])));
      mx = fmaxf(mx, fmaxf(fmaxf(sA[3][0], sA[3][1]), fmaxf(sA[3][2], sA[3][3])));
      mx = fmaxf(mx, __shfl_xor(mx, 16));
      mx = fmaxf(mx, __shfl_xor(mx, 32));
      if (__any(mx > mA)) {
        const float mnew = fmaxf(mA, mx);
        const float sc = exp2f(mA - mnew);
        mA = mnew;
        lA *= sc;
#pragma unroll
        for (int j = 0; j < 4; ++j) {
          accA[j][0] *= sc; accA[j][1] *= sc;
          accA[j][2] *= sc; accA[j][3] *= sc;
        }
      }
      float ps = 0.f;
#pragma unroll
      for (int j0 = 0; j0 < 4; ++j0) {
        const float p0 = exp2f(sA[j0][0] - mA);
        const float p1 = exp2f(sA[j0][1] - mA);
        const float p2 = exp2f(sA[j0][2] - mA);
        const float p3 = exp2f(sA[j0][3] - mA);
        ps += (p0 + p1) + (p2 + p3);
        WA[j0][0] = f2b(p0) | (f2b(p1) << 16);
        WA[j0][1] = f2b(p2) | (f2b(p3) << 16);
      }
      ps += __shfl_xor(ps, 16);
      ps += __shfl_xor(ps, 32);
      lA += ps;
    }
    // ---- softmax group B ----
    {
      float mx = fmaxf(fmaxf(sB[0][0], sB[0][1]), fmaxf(sB[0][2], sB[0][3]));
      mx = fmaxf(mx, fmaxf(fmaxf(sB[1][0], sB[1][1]), fmaxf(sB[1][2], sB[1][3])));
      mx = fmaxf(mx, fmaxf(fmaxf(sB[2][0], sB[2][1]), fmaxf(sB[2][2], sB[2][3])));
      mx = fmaxf(mx, fmaxf(fmaxf(sB[3][0], sB[3][1]), fmaxf(sB[3][2], sB[3][3])));
      mx = fmaxf(mx, __shfl_xor(mx, 16));
      mx = fmaxf(mx, __shfl_xor(mx, 32));
      if (__any(mx > mB)) {
        const float mnew = fmaxf(mB, mx);
        const float sc = exp2f(mB - mnew);
        mB = mnew;
        lB *= sc;
#pragma unroll
        for (int j = 0; j < 4; ++j) {
          accB[j][0] *= sc; accB[j][1] *= sc;
          accB[j][2] *= sc; accB[j][3] *= sc;
        }
      }
      float ps = 0.f;
#pragma unroll
      for (int j0 = 0; j0 < 4; ++j0) {
        const float p0 = exp2f(sB[j0][0] - mB);
        const float p1 = exp2f(sB[j0][1] - mB);
        const float p2 = exp2f(sB[j0][2] - mB);
        const float p3 = exp2f(sB[j0][3] - mB);
        ps += (p0 + p1) + (p2 + p3);
        WB[j0][0] = f2b(p0) | (f2b(p1) << 16);
        WB[j0][1] = f2b(p2) | (f2b(p3) << 16);
      }
      ps += __shfl_xor(ps, 16);
      ps += __shfl_xor(ps, 32);
      lB += ps;
    }

    // ---- P^T exchange + PV (V already in registers) ----
#pragma unroll
    for (int kc = 0; kc < 2; ++kc) {
      unsigned int wra[4], wrb[4];
#pragma unroll
      for (int wi = 0; wi < 4; ++wi) {
        const int src = lo + ((lane & 16) << 1) + ((wi >> 1) << 4);
        const unsigned int a0 = (unsigned int)__shfl((int)WA[2 * kc + 0][wi & 1], src);
        const unsigned int a1 = (unsigned int)__shfl((int)WA[2 * kc + 1][wi & 1], src);
        const unsigned int b0 = (unsigned int)__shfl((int)WB[2 * kc + 0][wi & 1], src);
        const unsigned int b1 = (unsigned int)__shfl((int)WB[2 * kc + 1][wi & 1], src);
        wra[wi] = (hi < 2) ? a0 : a1;
        wrb[wi] = (hi < 2) ? b0 : b1;
      }
      bf16x8 pBA, pBB;
      __builtin_memcpy(&pBA, wra, 16);
      __builtin_memcpy(&pBB, wrb, 16);
      __builtin_amdgcn_s_setprio(1);
#pragma unroll
      for (int j = 0; j < 4; ++j) {
        accA[j] = __builtin_amdgcn_mfma_f32_16x16x32_bf16(va[kc][j], pBA, accA[j], 0, 0, 0);
        accB[j] = __builtin_amdgcn_mfma_f32_16x16x32_bf16(va[kc][j], pBB, accB[j], 0, 0, 0);
      }
      __builtin_amdgcn_s_setprio(0);
    }
  }

  // ---- merge pass A ----
  if (hi == 0) { sml[0][w][lo] = mA; sml[1][w][lo] = lA; }
#pragma unroll
  for (int j = 0; j < 4; ++j)
    *(f32x4*)&sacc[w][lo][j * 16 + hi4] = accA[j];
  __syncthreads();
  {
    const int row = t >> 5;
    const int d0 = (t & 31) * 2;
    float mstar = sml[0][0][row];
#pragma unroll
    for (int ww = 1; ww < 8; ++ww) mstar = fmaxf(mstar, sml[0][ww][row]);
    float lstar = 0.f, o0 = 0.f, o1 = 0.f;
#pragma unroll
    for (int ww = 0; ww < 8; ++ww) {
      const float f = exp2f(sml[0][ww][row] - mstar);
      lstar += sml[1][ww][row] * f;
      const float2 a2 = *(const float2*)&sacc[ww][row][d0];
      o0 += a2.x * f;
      o1 += a2.y * f;
    }
    const float rl = 1.0f / lstar;
    float2 o; o.x = o0 * rl; o.y = o1 * rl;
    *(float2*)(out + ((size_t)batch * SS + q0 + row) * 64 + d0) = o;
  }
  __syncthreads();

  // ---- merge pass B ----
  if (hi == 0) { sml[0][w][lo] = mB; sml[1][w][lo] = lB; }
#pragma unroll
  for (int j = 0; j < 4; ++j)
    *(f32x4*)&sacc[w][lo][j * 16 + hi4] = accB[j];
  __syncthreads();
  {
    const int row = t >> 5;
    const int d0 = (t & 31) * 2;
    float mstar = sml[0][0][row];
#pragma unroll
    for (int ww = 1; ww < 8; ++ww) mstar = fmaxf(mstar, sml[0][ww][row]);
    float lstar = 0.f, o0 = 0.f, o1 = 0.f;
#pragma unroll
    for (int ww = 0; ww < 8; ++ww) {
      const float f = exp2f(sml[0][ww][row] - mstar);
      lstar += sml[1][ww][row] * f;
      const float2 a2 = *(const float2*)&sacc[ww][row][d0];
      o0 += a2.x * f;
      o1 += a2.y * f;
    }
    const float rl = 1.0f / lstar;
    float2 o; o.x = o0 * rl; o.y = o1 * rl;
    *(float2*)(out + ((size_t)batch * SS + q0 + 16 + row) * 64 + d0) = o;
  }
}

extern "C" void kernel_launch(void* const* d_in, const int* in_sizes, int n_in,
                              void* d_out, int out_size, void* d_ws, size_t ws_size,
                              hipStream_t stream) {
  const float* x  = (const float*)d_in[0];
  const float* Wq = (const float*)d_in[1];
  const float* Wk = (const float*)d_in[2];
  const float* Wv = (const float*)d_in[3];
  float* outp = (float*)d_out;

  unsigned short* qb = (unsigned short*)d_ws;           // 1 MB
  unsigned short* kb = qb + (size_t)BS * 64;            // 1 MB
  unsigned short* vt = kb + (size_t)BS * 64;            // 1 MB
  unsigned short* wt = vt + (size_t)BS * 64;            // 384 KB

  wt_prep<<<48, 256, 0, stream>>>(Wq, Wk, Wv, wt);
  qkv_mfma<<<BS / 32, 512, 0, stream>>>(x, wt, qb, kb, vt);
  attn_mfma<<<256, 512, 0, stream>>>(qb, kb, vt, outp);
}

// Round 21
// 41.873 us; speedup vs baseline: 1.0546x; 1.0546x over previous
//
#include <hip/hip_runtime.h>
#include <hip/hip_bf16.h>
#include <math.h>

#define BB 4
#define SS 2048
#define EE 1024
#define HH 64
#define BS (BB*SS)   // 8192 rows total

typedef __attribute__((ext_vector_type(8))) short bf16x8;
typedef __attribute__((ext_vector_type(4))) float f32x4;

static __device__ __forceinline__ unsigned int f2b(float f) {
  __hip_bfloat16 h = __float2bfloat16(f);
  unsigned short u;
  __builtin_memcpy(&u, &h, 2);
  return (unsigned int)u;
}

// ---------------------------------------------------------------------------
// Kernel 0: W transpose+convert.  wt[n][e] bf16, n = which*64 + h.
// Wq pre-scaled by (1/32)*log2e (exp2-domain scores).
// ---------------------------------------------------------------------------
__global__ __launch_bounds__(256) void wt_prep(const float* __restrict__ Wq,
                                               const float* __restrict__ Wk,
                                               const float* __restrict__ Wv,
                                               unsigned short* __restrict__ wt) {
  __shared__ float tile[64 * 69];
  const int blk = blockIdx.x;
  const int w = blk >> 4;
  const int et = blk & 15;
  const int t = threadIdx.x;
  const float* __restrict__ W = (w == 0) ? Wq : ((w == 1) ? Wk : Wv);

#pragma unroll
  for (int i = 0; i < 4; ++i) {
    const int idx = t + i * 256;
    const int row = idx >> 4;
    const int f4 = idx & 15;
    const float4 v = *(const float4*)(W + ((size_t)(et * 64 + row)) * 64 + f4 * 4);
    tile[row * 69 + f4 * 4 + 0] = v.x;
    tile[row * 69 + f4 * 4 + 1] = v.y;
    tile[row * 69 + f4 * 4 + 2] = v.z;
    tile[row * 69 + f4 * 4 + 3] = v.w;
  }
  __syncthreads();

  const float scale = (w == 0) ? 0.03125f * 1.4426950408889634f : 1.0f;
  const int h = t >> 2;
  const int eg = (t & 3) * 16;
  unsigned int o[8];
#pragma unroll
  for (int i = 0; i < 8; ++i) {
    const float a = tile[(eg + 2 * i + 0) * 69 + h] * scale;
    const float b = tile[(eg + 2 * i + 1) * 69 + h] * scale;
    o[i] = f2b(a) | (f2b(b) << 16);
  }
  unsigned short* dst = wt + ((size_t)(w * 64 + h)) * 1024 + et * 64 + eg;
  uint4 lo4; lo4.x = o[0]; lo4.y = o[1]; lo4.z = o[2]; lo4.w = o[3];
  uint4 hi4; hi4.x = o[4]; hi4.y = o[5]; hi4.z = o[6]; hi4.w = o[7];
  *(uint4*)dst = lo4;
  *(uint4*)(dst + 8) = hi4;
}

// ---------------------------------------------------------------------------
// Kernel A: QKV projection, bf16 MFMA — depth-3 x prefetch (measured best).
// 256 blocks x 512 threads, BM=32, BK=64, LDS double-buffered (x + W),
// XOR-swizzled. x (L3-resident, ~600-900cy) gets 3 compute-phases in flight;
// W (L2) 1-deep.
// ---------------------------------------------------------------------------
__global__ __launch_bounds__(512) void qkv_mfma(const float* __restrict__ x,
                                                const unsigned short* __restrict__ wt,
                                                unsigned short* __restrict__ qb,
                                                unsigned short* __restrict__ kbuf,
                                                unsigned short* __restrict__ vtb) {
  __shared__ char smem[57344];   // xs[2][4096] | ws[2][24576]
  const int t = threadIdx.x;
  const int blk = blockIdx.x;
  const int lane = t & 63;
  const int wv = t >> 6;
  const int wm = wv >> 2;        // 0..1
  const int wn = wv & 3;         // 0..3
  const int lo = lane & 15, hi = lane >> 4;

  const int xrow = t >> 4;       // 0..31
  const int xf4 = t & 15;
  const int wr0 = t >> 3;        // 0..63
  const int wc = t & 7;

  const float* __restrict__ xsrc = x + ((size_t)blk * 32 + xrow) * 1024 + xf4 * 4;
  const unsigned short* __restrict__ wsrc = wt + (size_t)wr0 * 1024 + wc * 8;

  float4 xpre[3];
  bf16x8 wrg[3];
  f32x4 acc[3] = {};

#define LOADX(slot, kt) xpre[slot] = *(const float4*)(xsrc + (kt) * 64)
#define LOADW(kt)                                                     \
  do {                                                                \
    wrg[0] = *(const bf16x8*)(wsrc + (kt) * 64);                      \
    wrg[1] = *(const bf16x8*)(wsrc + 64 * 1024 + (kt) * 64);          \
    wrg[2] = *(const bf16x8*)(wsrc + 128 * 1024 + (kt) * 64);         \
  } while (0)

#define WRITEX(buf, slot)                                                    \
  do {                                                                       \
    uint2 pv;                                                                \
    pv.x = f2b(xpre[slot].x) | (f2b(xpre[slot].y) << 16);                    \
    pv.y = f2b(xpre[slot].z) | (f2b(xpre[slot].w) << 16);                    \
    *(uint2*)&smem[(buf) * 4096 + xrow * 128 +                               \
                   ((xf4 * 8) ^ ((xrow & 7) << 4))] = pv;                    \
  } while (0)

#define WRITEW(buf)                                                          \
  do {                                                                       \
    char* wb = &smem[8192 + (buf) * 24576];                                  \
    const int sw = (wc * 16) ^ ((wr0 & 7) << 4);                             \
    *(bf16x8*)&wb[(wr0 + 0) * 128 + sw] = wrg[0];                            \
    *(bf16x8*)&wb[(wr0 + 64) * 128 + sw] = wrg[1];                           \
    *(bf16x8*)&wb[(wr0 + 128) * 128 + sw] = wrg[2];                          \
  } while (0)

  LOADX(0, 0); LOADX(1, 1); LOADX(2, 2);
  LOADW(0);
  WRITEX(0, 0);
  WRITEW(0);
  __syncthreads();

  const int arow = wm * 16 + lo;
  const int aswz = (arow & 7) << 4;

#pragma unroll
  for (int kt = 0; kt < 16; ++kt) {
    const int cur = kt & 1;
    if (kt + 1 < 16) LOADW(kt + 1);
    if (kt + 3 < 16) LOADX(kt % 3, kt + 3);

    const char* xb = &smem[cur * 4096];
    const char* wb = &smem[8192 + cur * 24576];
    const bf16x8 a0 = *(const bf16x8*)&xb[arow * 128 + ((hi * 16) ^ aswz)];
    const bf16x8 a1 = *(const bf16x8*)&xb[arow * 128 + ((64 + hi * 16) ^ aswz)];
#pragma unroll
    for (int nf = 0; nf < 3; ++nf) {
      const int brow = wn * 48 + nf * 16 + lo;
      const int bswz = (brow & 7) << 4;
      const bf16x8 b0 = *(const bf16x8*)&wb[brow * 128 + ((hi * 16) ^ bswz)];
      const bf16x8 b1 = *(const bf16x8*)&wb[brow * 128 + ((64 + hi * 16) ^ bswz)];
      acc[nf] = __builtin_amdgcn_mfma_f32_16x16x32_bf16(a0, b0, acc[nf], 0, 0, 0);
      acc[nf] = __builtin_amdgcn_mfma_f32_16x16x32_bf16(a1, b1, acc[nf], 0, 0, 0);
    }

    if (kt + 1 < 16) {
      WRITEX(cur ^ 1, (kt + 1) % 3);
      WRITEW(cur ^ 1);
    }
    __syncthreads();
  }

  const int m0 = blk * 32 + wm * 16 + hi * 4;
#pragma unroll
  for (int nf = 0; nf < 3; ++nf) {
    const int nb = wn * 48 + nf * 16;
    const int which = nb >> 6;
    const int h = (nb & 63) + lo;
#pragma unroll
    for (int r = 0; r < 4; ++r) {
      const int row = m0 + r;
      const unsigned short v = (unsigned short)f2b(acc[nf][r]);
      if (which == 0) qb[(size_t)row * 64 + h] = v;
      else if (which == 1) kbuf[(size_t)row * 64 + h] = v;
      else vtb[((size_t)(row >> 11) * 64 + h) * 2048 + (row & 2047)] = v;
    }
  }
#undef LOADX
#undef LOADW
#undef WRITEX
#undef WRITEW
}

// ---------------------------------------------------------------------------
// Kernel B: causal flash attention — measured-best structure (R11/R18):
// adjacent 2-q-group + snake, 8-way split-K, V-frag hoist after QK^T,
// setprio around MFMA clusters, exp2 softmax, exact skip-rescale.
// (K prefetch measured negative twice; V-first reorder null — both omitted.)
// ---------------------------------------------------------------------------
__global__ __launch_bounds__(512) void attn_mfma(const unsigned short* __restrict__ qb,
                                                 const unsigned short* __restrict__ kbuf,
                                                 const unsigned short* __restrict__ vt,
                                                 float* __restrict__ out) {
  __shared__ __align__(16) float sacc[8][16][64];  // 32 KB (reused per group)
  __shared__ float sml[2][8][16];

  const int t = threadIdx.x;
  const int lane = t & 63;
  const int w = t >> 6;            // 0..7 (split-K wave)
  const int lo = lane & 15, hi = lane >> 4;
  const int hi4 = hi * 4;

  const int blk = blockIdx.x;      // 0..255
  const int batch = blk & 3;
  const int tt = blk >> 2;         // 0..63
  const int qt = (tt & 1) ? (63 - (tt >> 1)) : (tt >> 1);  // snake
  const int q0 = qt * 32;

  const unsigned short* Qb = qb   + (size_t)batch * SS * 64;
  const unsigned short* Kb = kbuf + (size_t)batch * SS * 64;
  const unsigned short* Vt = vt   + (size_t)batch * 64 * SS;

  const int qA = q0 + lo;
  const int qBr = q0 + 16 + lo;

  const bf16x8 qf0a = *(const bf16x8*)(Qb + (size_t)qA * 64 + hi * 8);
  const bf16x8 qf1a = *(const bf16x8*)(Qb + (size_t)qA * 64 + 32 + hi * 8);
  const bf16x8 qf0b = *(const bf16x8*)(Qb + (size_t)qBr * 64 + hi * 8);
  const bf16x8 qf1b = *(const bf16x8*)(Qb + (size_t)qBr * 64 + 32 + hi * 8);

  f32x4 accA[4] = {}, accB[4] = {};
  float mA = -1e30f, lA = 0.f, mB = -1e30f, lB = 0.f;

  const int kend = q0 + 32;
  for (int kbase = w * 64; kbase < kend; kbase += 512) {
    // ---- QK^T for both groups (K frags shared) ----
    f32x4 sA[4], sB[4];
    __builtin_amdgcn_s_setprio(1);
#pragma unroll
    for (int j0 = 0; j0 < 4; ++j0) {
      const unsigned short* Krow = Kb + (size_t)(kbase + j0 * 16 + lo) * 64 + hi * 8;
      const bf16x8 ka = *(const bf16x8*)(Krow);
      const bf16x8 kb2 = *(const bf16x8*)(Krow + 32);
      f32x4 ca = {}, cb = {};
      ca = __builtin_amdgcn_mfma_f32_16x16x32_bf16(ka, qf0a, ca, 0, 0, 0);
      ca = __builtin_amdgcn_mfma_f32_16x16x32_bf16(kb2, qf1a, ca, 0, 0, 0);
      cb = __builtin_amdgcn_mfma_f32_16x16x32_bf16(ka, qf0b, cb, 0, 0, 0);
      cb = __builtin_amdgcn_mfma_f32_16x16x32_bf16(kb2, qf1b, cb, 0, 0, 0);
      sA[j0] = ca; sB[j0] = cb;
    }
    __builtin_amdgcn_s_setprio(0);

    // ---- V-frag hoist ----
    bf16x8 va[2][4];
#pragma unroll
    for (int kc = 0; kc < 2; ++kc)
#pragma unroll
      for (int j = 0; j < 4; ++j)
        va[kc][j] = *(const bf16x8*)(Vt + (size_t)(j * 16 + lo) * SS +
                                     kbase + kc * 32 + hi * 8);

    // ---- causal mask ----
    if (kbase + 64 > q0) {
#pragma unroll
      for (int j0 = 0; j0 < 4; ++j0)
#pragma unroll
        for (int r = 0; r < 4; ++r) {
          const int key = kbase + j0 * 16 + hi4 + r;
          sA[j0][r] = (key > qA) ? -1e30f : sA[j0][r];
          sB[j0][r] = (key > qBr) ? -1e30f : sB[j0][r];
        }
    }

    // ---- softmax group A ----
    unsigned int WA[4][2], WB[4][2];
    {
      float mx = fmaxf(fmaxf(sA[0][0], sA[0][1]), fmaxf(sA[0][2], sA[0][3]));
      mx = fmaxf(mx, fmaxf(fmaxf(sA[1][0], sA[1][1]), fmaxf(sA[1][2], sA[1][3])));
      mx = fmaxf(mx, fmaxf(fmaxf(sA[2][0], sA[2][1]), fmaxf(sA[2][2], sA[2][3])));
      mx = fmaxf(mx, fmaxf(fmaxf(sA[3][0], sA[3][1]), fmaxf(sA[3][2], sA[3][3])));
      mx = fmaxf(mx, __shfl_xor(mx, 16));
      mx = fmaxf(mx, __shfl_xor(mx, 32));
      if (__any(mx > mA)) {
        const float mnew = fmaxf(mA, mx);
        const float sc = exp2f(mA - mnew);
        mA = mnew;
        lA *= sc;
#pragma unroll
        for (int j = 0; j < 4; ++j) {
          accA[j][0] *= sc; accA[j][1] *= sc;
          accA[j][2] *= sc; accA[j][3] *= sc;
        }
      }
      float ps = 0.f;
#pragma unroll
      for (int j0 = 0; j0 < 4; ++j0) {
        const float p0 = exp2f(sA[j0][0] - mA);
        const float p1 = exp2f(sA[j0][1] - mA);
        const float p2 = exp2f(sA[j0][2] - mA);
        const float p3 = exp2f(sA[j0][3] - mA);
        ps += (p0 + p1) + (p2 + p3);
        WA[j0][0] = f2b(p0) | (f2b(p1) << 16);
        WA[j0][1] = f2b(p2) | (f2b(p3) << 16);
      }
      ps += __shfl_xor(ps, 16);
      ps += __shfl_xor(ps, 32);
      lA += ps;
    }
    // ---- softmax group B ----
    {
      float mx = fmaxf(fmaxf(sB[0][0], sB[0][1]), fmaxf(sB[0][2], sB[0][3]));
      mx = fmaxf(mx, fmaxf(fmaxf(sB[1][0], sB[1][1]), fmaxf(sB[1][2], sB[1][3])));
      mx = fmaxf(mx, fmaxf(fmaxf(sB[2][0], sB[2][1]), fmaxf(sB[2][2], sB[2][3])));
      mx = fmaxf(mx, fmaxf(fmaxf(sB[3][0], sB[3][1]), fmaxf(sB[3][2], sB[3][3])));
      mx = fmaxf(mx, __shfl_xor(mx, 16));
      mx = fmaxf(mx, __shfl_xor(mx, 32));
      if (__any(mx > mB)) {
        const float mnew = fmaxf(mB, mx);
        const float sc = exp2f(mB - mnew);
        mB = mnew;
        lB *= sc;
#pragma unroll
        for (int j = 0; j < 4; ++j) {
          accB[j][0] *= sc; accB[j][1] *= sc;
          accB[j][2] *= sc; accB[j][3] *= sc;
        }
      }
      float ps = 0.f;
#pragma unroll
      for (int j0 = 0; j0 < 4; ++j0) {
        const float p0 = exp2f(sB[j0][0] - mB);
        const float p1 = exp2f(sB[j0][1] - mB);
        const float p2 = exp2f(sB[j0][2] - mB);
        const float p3 = exp2f(sB[j0][3] - mB);
        ps += (p0 + p1) + (p2 + p3);
        WB[j0][0] = f2b(p0) | (f2b(p1) << 16);
        WB[j0][1] = f2b(p2) | (f2b(p3) << 16);
      }
      ps += __shfl_xor(ps, 16);
      ps += __shfl_xor(ps, 32);
      lB += ps;
    }

    // ---- P^T exchange + PV (V already in registers) ----
#pragma unroll
    for (int kc = 0; kc < 2; ++kc) {
      unsigned int wra[4], wrb[4];
#pragma unroll
      for (int wi = 0; wi < 4; ++wi) {
        const int src = lo + ((lane & 16) << 1) + ((wi >> 1) << 4);
        const unsigned int a0 = (unsigned int)__shfl((int)WA[2 * kc + 0][wi & 1], src);
        const unsigned int a1 = (unsigned int)__shfl((int)WA[2 * kc + 1][wi & 1], src);
        const unsigned int b0 = (unsigned int)__shfl((int)WB[2 * kc + 0][wi & 1], src);
        const unsigned int b1 = (unsigned int)__shfl((int)WB[2 * kc + 1][wi & 1], src);
        wra[wi] = (hi < 2) ? a0 : a1;
        wrb[wi] = (hi < 2) ? b0 : b1;
      }
      bf16x8 pBA, pBB;
      __builtin_memcpy(&pBA, wra, 16);
      __builtin_memcpy(&pBB, wrb, 16);
      __builtin_amdgcn_s_setprio(1);
#pragma unroll
      for (int j = 0; j < 4; ++j) {
        accA[j] = __builtin_amdgcn_mfma_f32_16x16x32_bf16(va[kc][j], pBA, accA[j], 0, 0, 0);
        accB[j] = __builtin_amdgcn_mfma_f32_16x16x32_bf16(va[kc][j], pBB, accB[j], 0, 0, 0);
      }
      __builtin_amdgcn_s_setprio(0);
    }
  }

  // ---- merge pass A ----
  if (hi == 0) { sml[0][w][lo] = mA; sml[1][w][lo] = lA; }
#pragma unroll
  for (int j = 0; j < 4; ++j)
    *(f32x4*)&sacc[w][lo][j * 16 + hi4] = accA[j];
  __syncthreads();
  {
    const int row = t >> 5;
    const int d0 = (t & 31) * 2;
    float mstar = sml[0][0][row];
#pragma unroll
    for (int ww = 1; ww < 8; ++ww) mstar = fmaxf(mstar, sml[0][ww][row]);
    float lstar = 0.f, o0 = 0.f, o1 = 0.f;
#pragma unroll
    for (int ww = 0; ww < 8; ++ww) {
      const float f = exp2f(sml[0][ww][row] - mstar);
      lstar += sml[1][ww][row] * f;
      const float2 a2 = *(const float2*)&sacc[ww][row][d0];
      o0 += a2.x * f;
      o1 += a2.y * f;
    }
    const float rl = 1.0f / lstar;
    float2 o; o.x = o0 * rl; o.y = o1 * rl;
    *(float2*)(out + ((size_t)batch * SS + q0 + row) * 64 + d0) = o;
  }
  __syncthreads();

  // ---- merge pass B ----
  if (hi == 0) { sml[0][w][lo] = mB; sml[1][w][lo] = lB; }
#pragma unroll
  for (int j = 0; j < 4; ++j)
    *(f32x4*)&sacc[w][lo][j * 16 + hi4] = accB[j];
  __syncthreads();
  {
    const int row = t >> 5;
    const int d0 = (t & 31) * 2;
    float mstar = sml[0][0][row];
#pragma unroll
    for (int ww = 1; ww < 8; ++ww) mstar = fmaxf(mstar, sml[0][ww][row]);
    float lstar = 0.f, o0 = 0.f, o1 = 0.f;
#pragma unroll
    for (int ww = 0; ww < 8; ++ww) {
      const float f = exp2f(sml[0][ww][row] - mstar);
      lstar += sml[1][ww][row] * f;
      const float2 a2 = *(const float2*)&sacc[ww][row][d0];
      o0 += a2.x * f;
      o1 += a2.y * f;
    }
    const float rl = 1.0f / lstar;
    float2 o; o.x = o0 * rl; o.y = o1 * rl;
    *(float2*)(out + ((size_t)batch * SS + q0 + 16 + row) * 64 + d0) = o;
  }
}

extern "C" void kernel_launch(void* const* d_in, const int* in_sizes, int n_in,
                              void* d_out, int out_size, void* d_ws, size_t ws_size,
                              hipStream_t stream) {
  const float* x  = (const float*)d_in[0];
  const float* Wq = (const float*)d_in[1];
  const float* Wk = (const float*)d_in[2];
  const float* Wv = (const float*)d_in[3];
  float* outp = (float*)d_out;

  unsigned short* qb = (unsigned short*)d_ws;           // 1 MB
  unsigned short* kb = qb + (size_t)BS * 64;            // 1 MB
  unsigned short* vt = kb + (size_t)BS * 64;            // 1 MB
  unsigned short* wt = vt + (size_t)BS * 64;            // 384 KB

  wt_prep<<<48, 256, 0, stream>>>(Wq, Wk, Wv, wt);
  qkv_mfma<<<BS / 32, 512, 0, stream>>>(x, wt, qb, kb, vt);
  attn_mfma<<<256, 512, 0, stream>>>(qb, kb, vt, outp);
}

// Round 22
// 41.722 us; speedup vs baseline: 1.0584x; 1.0036x over previous
//
#include <hip/hip_runtime.h>
#include <hip/hip_bf16.h>
#include <math.h>

#define BB 4
#define SS 2048
#define EE 1024
#define HH 64
#define BS (BB*SS)   // 8192 rows total

typedef __attribute__((ext_vector_type(8))) short bf16x8;
typedef __attribute__((ext_vector_type(4))) float f32x4;

static __device__ __forceinline__ unsigned int f2b(float f) {
  __hip_bfloat16 h = __float2bfloat16(f);
  unsigned short u;
  __builtin_memcpy(&u, &h, 2);
  return (unsigned int)u;
}

// ---------------------------------------------------------------------------
// FINAL CONFIGURATION (measured 41.9-42.2 us over two runs; 5.5x vs fp32
// baseline). Three dispatches:
//   wt_prep  : W transpose+convert, Wq pre-scaled by (1/32)*log2e.
//   qkv_mfma : bf16 MFMA GEMM, BM=32/BK=64, LDS dbuf + XOR swizzle,
//              depth-3 x prefetch (x is L3-resident; 3 phases in flight).
//   attn_mfma: causal flash, 2 adjacent q-groups/block (shared K/V loads),
//              8-way split-K, V-hoist, setprio, exp2 softmax, skip-rescale.
// Measured-dead ends: fusion (3x), K-reg prefetch (2x), antipodal pairing,
// global_load_lds W staging, integrated W transform.
// ---------------------------------------------------------------------------
__global__ __launch_bounds__(256) void wt_prep(const float* __restrict__ Wq,
                                               const float* __restrict__ Wk,
                                               const float* __restrict__ Wv,
                                               unsigned short* __restrict__ wt) {
  __shared__ float tile[64 * 69];
  const int blk = blockIdx.x;
  const int w = blk >> 4;
  const int et = blk & 15;
  const int t = threadIdx.x;
  const float* __restrict__ W = (w == 0) ? Wq : ((w == 1) ? Wk : Wv);

#pragma unroll
  for (int i = 0; i < 4; ++i) {
    const int idx = t + i * 256;
    const int row = idx >> 4;
    const int f4 = idx & 15;
    const float4 v = *(const float4*)(W + ((size_t)(et * 64 + row)) * 64 + f4 * 4);
    tile[row * 69 + f4 * 4 + 0] = v.x;
    tile[row * 69 + f4 * 4 + 1] = v.y;
    tile[row * 69 + f4 * 4 + 2] = v.z;
    tile[row * 69 + f4 * 4 + 3] = v.w;
  }
  __syncthreads();

  const float scale = (w == 0) ? 0.03125f * 1.4426950408889634f : 1.0f;
  const int h = t >> 2;
  const int eg = (t & 3) * 16;
  unsigned int o[8];
#pragma unroll
  for (int i = 0; i < 8; ++i) {
    const float a = tile[(eg + 2 * i + 0) * 69 + h] * scale;
    const float b = tile[(eg + 2 * i + 1) * 69 + h] * scale;
    o[i] = f2b(a) | (f2b(b) << 16);
  }
  unsigned short* dst = wt + ((size_t)(w * 64 + h)) * 1024 + et * 64 + eg;
  uint4 lo4; lo4.x = o[0]; lo4.y = o[1]; lo4.z = o[2]; lo4.w = o[3];
  uint4 hi4; hi4.x = o[4]; hi4.y = o[5]; hi4.z = o[6]; hi4.w = o[7];
  *(uint4*)dst = lo4;
  *(uint4*)(dst + 8) = hi4;
}

__global__ __launch_bounds__(512) void qkv_mfma(const float* __restrict__ x,
                                                const unsigned short* __restrict__ wt,
                                                unsigned short* __restrict__ qb,
                                                unsigned short* __restrict__ kbuf,
                                                unsigned short* __restrict__ vtb) {
  __shared__ char smem[57344];   // xs[2][4096] | ws[2][24576]
  const int t = threadIdx.x;
  const int blk = blockIdx.x;
  const int lane = t & 63;
  const int wv = t >> 6;
  const int wm = wv >> 2;        // 0..1
  const int wn = wv & 3;         // 0..3
  const int lo = lane & 15, hi = lane >> 4;

  const int xrow = t >> 4;       // 0..31
  const int xf4 = t & 15;
  const int wr0 = t >> 3;        // 0..63
  const int wc = t & 7;

  const float* __restrict__ xsrc = x + ((size_t)blk * 32 + xrow) * 1024 + xf4 * 4;
  const unsigned short* __restrict__ wsrc = wt + (size_t)wr0 * 1024 + wc * 8;

  float4 xpre[3];
  bf16x8 wrg[3];
  f32x4 acc[3] = {};

#define LOADX(slot, kt) xpre[slot] = *(const float4*)(xsrc + (kt) * 64)
#define LOADW(kt)                                                     \
  do {                                                                \
    wrg[0] = *(const bf16x8*)(wsrc + (kt) * 64);                      \
    wrg[1] = *(const bf16x8*)(wsrc + 64 * 1024 + (kt) * 64);          \
    wrg[2] = *(const bf16x8*)(wsrc + 128 * 1024 + (kt) * 64);         \
  } while (0)

#define WRITEX(buf, slot)                                                    \
  do {                                                                       \
    uint2 pv;                                                                \
    pv.x = f2b(xpre[slot].x) | (f2b(xpre[slot].y) << 16);                    \
    pv.y = f2b(xpre[slot].z) | (f2b(xpre[slot].w) << 16);                    \
    *(uint2*)&smem[(buf) * 4096 + xrow * 128 +                               \
                   ((xf4 * 8) ^ ((xrow & 7) << 4))] = pv;                    \
  } while (0)

#define WRITEW(buf)                                                          \
  do {                                                                       \
    char* wb = &smem[8192 + (buf) * 24576];                                  \
    const int sw = (wc * 16) ^ ((wr0 & 7) << 4);                             \
    *(bf16x8*)&wb[(wr0 + 0) * 128 + sw] = wrg[0];                            \
    *(bf16x8*)&wb[(wr0 + 64) * 128 + sw] = wrg[1];                           \
    *(bf16x8*)&wb[(wr0 + 128) * 128 + sw] = wrg[2];                          \
  } while (0)

  LOADX(0, 0); LOADX(1, 1); LOADX(2, 2);
  LOADW(0);
  WRITEX(0, 0);
  WRITEW(0);
  __syncthreads();

  const int arow = wm * 16 + lo;
  const int aswz = (arow & 7) << 4;

#pragma unroll
  for (int kt = 0; kt < 16; ++kt) {
    const int cur = kt & 1;
    if (kt + 1 < 16) LOADW(kt + 1);
    if (kt + 3 < 16) LOADX(kt % 3, kt + 3);

    const char* xb = &smem[cur * 4096];
    const char* wb = &smem[8192 + cur * 24576];
    const bf16x8 a0 = *(const bf16x8*)&xb[arow * 128 + ((hi * 16) ^ aswz)];
    const bf16x8 a1 = *(const bf16x8*)&xb[arow * 128 + ((64 + hi * 16) ^ aswz)];
#pragma unroll
    for (int nf = 0; nf < 3; ++nf) {
      const int brow = wn * 48 + nf * 16 + lo;
      const int bswz = (brow & 7) << 4;
      const bf16x8 b0 = *(const bf16x8*)&wb[brow * 128 + ((hi * 16) ^ bswz)];
      const bf16x8 b1 = *(const bf16x8*)&wb[brow * 128 + ((64 + hi * 16) ^ bswz)];
      acc[nf] = __builtin_amdgcn_mfma_f32_16x16x32_bf16(a0, b0, acc[nf], 0, 0, 0);
      acc[nf] = __builtin_amdgcn_mfma_f32_16x16x32_bf16(a1, b1, acc[nf], 0, 0, 0);
    }

    if (kt + 1 < 16) {
      WRITEX(cur ^ 1, (kt + 1) % 3);
      WRITEW(cur ^ 1);
    }
    __syncthreads();
  }

  const int m0 = blk * 32 + wm * 16 + hi * 4;
#pragma unroll
  for (int nf = 0; nf < 3; ++nf) {
    const int nb = wn * 48 + nf * 16;
    const int which = nb >> 6;
    const int h = (nb & 63) + lo;
#pragma unroll
    for (int r = 0; r < 4; ++r) {
      const int row = m0 + r;
      const unsigned short v = (unsigned short)f2b(acc[nf][r]);
      if (which == 0) qb[(size_t)row * 64 + h] = v;
      else if (which == 1) kbuf[(size_t)row * 64 + h] = v;
      else vtb[((size_t)(row >> 11) * 64 + h) * 2048 + (row & 2047)] = v;
    }
  }
#undef LOADX
#undef LOADW
#undef WRITEX
#undef WRITEW
}

__global__ __launch_bounds__(512) void attn_mfma(const unsigned short* __restrict__ qb,
                                                 const unsigned short* __restrict__ kbuf,
                                                 const unsigned short* __restrict__ vt,
                                                 float* __restrict__ out) {
  __shared__ __align__(16) float sacc[8][16][64];  // 32 KB (reused per group)
  __shared__ float sml[2][8][16];

  const int t = threadIdx.x;
  const int lane = t & 63;
  const int w = t >> 6;            // 0..7 (split-K wave)
  const int lo = lane & 15, hi = lane >> 4;
  const int hi4 = hi * 4;

  const int blk = blockIdx.x;      // 0..255
  const int batch = blk & 3;
  const int tt = blk >> 2;         // 0..63
  const int qt = (tt & 1) ? (63 - (tt >> 1)) : (tt >> 1);  // snake
  const int q0 = qt * 32;

  const unsigned short* Qb = qb   + (size_t)batch * SS * 64;
  const unsigned short* Kb = kbuf + (size_t)batch * SS * 64;
  const unsigned short* Vt = vt   + (size_t)batch * 64 * SS;

  const int qA = q0 + lo;
  const int qBr = q0 + 16 + lo;

  const bf16x8 qf0a = *(const bf16x8*)(Qb + (size_t)qA * 64 + hi * 8);
  const bf16x8 qf1a = *(const bf16x8*)(Qb + (size_t)qA * 64 + 32 + hi * 8);
  const bf16x8 qf0b = *(const bf16x8*)(Qb + (size_t)qBr * 64 + hi * 8);
  const bf16x8 qf1b = *(const bf16x8*)(Qb + (size_t)qBr * 64 + 32 + hi * 8);

  f32x4 accA[4] = {}, accB[4] = {};
  float mA = -1e30f, lA = 0.f, mB = -1e30f, lB = 0.f;

  const int kend = q0 + 32;
  for (int kbase = w * 64; kbase < kend; kbase += 512) {
    // ---- QK^T for both groups (K frags shared) ----
    f32x4 sA[4], sB[4];
    __builtin_amdgcn_s_setprio(1);
#pragma unroll
    for (int j0 = 0; j0 < 4; ++j0) {
      const unsigned short* Krow = Kb + (size_t)(kbase + j0 * 16 + lo) * 64 + hi * 8;
      const bf16x8 ka = *(const bf16x8*)(Krow);
      const bf16x8 kb2 = *(const bf16x8*)(Krow + 32);
      f32x4 ca = {}, cb = {};
      ca = __builtin_amdgcn_mfma_f32_16x16x32_bf16(ka, qf0a, ca, 0, 0, 0);
      ca = __builtin_amdgcn_mfma_f32_16x16x32_bf16(kb2, qf1a, ca, 0, 0, 0);
      cb = __builtin_amdgcn_mfma_f32_16x16x32_bf16(ka, qf0b, cb, 0, 0, 0);
      cb = __builtin_amdgcn_mfma_f32_16x16x32_bf16(kb2, qf1b, cb, 0, 0, 0);
      sA[j0] = ca; sB[j0] = cb;
    }
    __builtin_amdgcn_s_setprio(0);

    // ---- V-frag hoist ----
    bf16x8 va[2][4];
#pragma unroll
    for (int kc = 0; kc < 2; ++kc)
#pragma unroll
      for (int j = 0; j < 4; ++j)
        va[kc][j] = *(const bf16x8*)(Vt + (size_t)(j * 16 + lo) * SS +
                                     kbase + kc * 32 + hi * 8);

    // ---- causal mask ----
    if (kbase + 64 > q0) {
#pragma unroll
      for (int j0 = 0; j0 < 4; ++j0)
#pragma unroll
        for (int r = 0; r < 4; ++r) {
          const int key = kbase + j0 * 16 + hi4 + r;
          sA[j0][r] = (key > qA) ? -1e30f : sA[j0][r];
          sB[j0][r] = (key > qBr) ? -1e30f : sB[j0][r];
        }
    }

    // ---- softmax group A ----
    unsigned int WA[4][2], WB[4][2];
    {
      float mx = fmaxf(fmaxf(sA[0][0], sA[0][1]), fmaxf(sA[0][2], sA[0][3]));
      mx = fmaxf(mx, fmaxf(fmaxf(sA[1][0], sA[1][1]), fmaxf(sA[1][2], sA[1][3])));
      mx = fmaxf(mx, fmaxf(fmaxf(sA[2][0], sA[2][1]), fmaxf(sA[2][2], sA[2][3])));
      mx = fmaxf(mx, fmaxf(fmaxf(sA[3][0], sA[3][1]), fmaxf(sA[3][2], sA[3][3])));
      mx = fmaxf(mx, __shfl_xor(mx, 16));
      mx = fmaxf(mx, __shfl_xor(mx, 32));
      if (__any(mx > mA)) {
        const float mnew = fmaxf(mA, mx);
        const float sc = exp2f(mA - mnew);
        mA = mnew;
        lA *= sc;
#pragma unroll
        for (int j = 0; j < 4; ++j) {
          accA[j][0] *= sc; accA[j][1] *= sc;
          accA[j][2] *= sc; accA[j][3] *= sc;
        }
      }
      float ps = 0.f;
#pragma unroll
      for (int j0 = 0; j0 < 4; ++j0) {
        const float p0 = exp2f(sA[j0][0] - mA);
        const float p1 = exp2f(sA[j0][1] - mA);
        const float p2 = exp2f(sA[j0][2] - mA);
        const float p3 = exp2f(sA[j0][3] - mA);
        ps += (p0 + p1) + (p2 + p3);
        WA[j0][0] = f2b(p0) | (f2b(p1) << 16);
        WA[j0][1] = f2b(p2) | (f2b(p3) << 16);
      }
      ps += __shfl_xor(ps, 16);
      ps += __shfl_xor(ps, 32);
      lA += ps;
    }
    // ---- softmax group B ----
    {
      float mx = fmaxf(fmaxf(sB[0][0], sB[0][1]), fmaxf(sB[0][2], sB[0][3]));
      mx = fmaxf(mx, fmaxf(fmaxf(sB[1][0], sB[1][1]), fmaxf(sB[1][2], sB[1][3])));
      mx = fmaxf(mx, fmaxf(fmaxf(sB[2][0], sB[2][1]), fmaxf(sB[2][2], sB[2][3])));
      mx = fmaxf(mx, fmaxf(fmaxf(sB[3][0], sB[3][1]), fmaxf(sB[3][2], sB[3][3])));
      mx = fmaxf(mx, __shfl_xor(mx, 16));
      mx = fmaxf(mx, __shfl_xor(mx, 32));
      if (__any(mx > mB)) {
        const float mnew = fmaxf(mB, mx);
        const float sc = exp2f(mB - mnew);
        mB = mnew;
        lB *= sc;
#pragma unroll
        for (int j = 0; j < 4; ++j) {
          accB[j][0] *= sc; accB[j][1] *= sc;
          accB[j][2] *= sc; accB[j][3] *= sc;
        }
      }
      float ps = 0.f;
#pragma unroll
      for (int j0 = 0; j0 < 4; ++j0) {
        const float p0 = exp2f(sB[j0][0] - mB);
        const float p1 = exp2f(sB[j0][1] - mB);
        const float p2 = exp2f(sB[j0][2] - mB);
        const float p3 = exp2f(sB[j0][3] - mB);
        ps += (p0 + p1) + (p2 + p3);
        WB[j0][0] = f2b(p0) | (f2b(p1) << 16);
        WB[j0][1] = f2b(p2) | (f2b(p3) << 16);
      }
      ps += __shfl_xor(ps, 16);
      ps += __shfl_xor(ps, 32);
      lB += ps;
    }

    // ---- P^T exchange + PV (V already in registers) ----
#pragma unroll
    for (int kc = 0; kc < 2; ++kc) {
      unsigned int wra[4], wrb[4];
#pragma unroll
      for (int wi = 0; wi < 4; ++wi) {
        const int src = lo + ((lane & 16) << 1) + ((wi >> 1) << 4);
        const unsigned int a0 = (unsigned int)__shfl((int)WA[2 * kc + 0][wi & 1], src);
        const unsigned int a1 = (unsigned int)__shfl((int)WA[2 * kc + 1][wi & 1], src);
        const unsigned int b0 = (unsigned int)__shfl((int)WB[2 * kc + 0][wi & 1], src);
        const unsigned int b1 = (unsigned int)__shfl((int)WB[2 * kc + 1][wi & 1], src);
        wra[wi] = (hi < 2) ? a0 : a1;
        wrb[wi] = (hi < 2) ? b0 : b1;
      }
      bf16x8 pBA, pBB;
      __builtin_memcpy(&pBA, wra, 16);
      __builtin_memcpy(&pBB, wrb, 16);
      __builtin_amdgcn_s_setprio(1);
#pragma unroll
      for (int j = 0; j < 4; ++j) {
        accA[j] = __builtin_amdgcn_mfma_f32_16x16x32_bf16(va[kc][j], pBA, accA[j], 0, 0, 0);
        accB[j] = __builtin_amdgcn_mfma_f32_16x16x32_bf16(va[kc][j], pBB, accB[j], 0, 0, 0);
      }
      __builtin_amdgcn_s_setprio(0);
    }
  }

  // ---- merge pass A ----
  if (hi == 0) { sml[0][w][lo] = mA; sml[1][w][lo] = lA; }
#pragma unroll
  for (int j = 0; j < 4; ++j)
    *(f32x4*)&sacc[w][lo][j * 16 + hi4] = accA[j];
  __syncthreads();
  {
    const int row = t >> 5;
    const int d0 = (t & 31) * 2;
    float mstar = sml[0][0][row];
#pragma unroll
    for (int ww = 1; ww < 8; ++ww) mstar = fmaxf(mstar, sml[0][ww][row]);
    float lstar = 0.f, o0 = 0.f, o1 = 0.f;
#pragma unroll
    for (int ww = 0; ww < 8; ++ww) {
      const float f = exp2f(sml[0][ww][row] - mstar);
      lstar += sml[1][ww][row] * f;
      const float2 a2 = *(const float2*)&sacc[ww][row][d0];
      o0 += a2.x * f;
      o1 += a2.y * f;
    }
    const float rl = 1.0f / lstar;
    float2 o; o.x = o0 * rl; o.y = o1 * rl;
    *(float2*)(out + ((size_t)batch * SS + q0 + row) * 64 + d0) = o;
  }
  __syncthreads();

  // ---- merge pass B ----
  if (hi == 0) { sml[0][w][lo] = mB; sml[1][w][lo] = lB; }
#pragma unroll
  for (int j = 0; j < 4; ++j)
    *(f32x4*)&sacc[w][lo][j * 16 + hi4] = accB[j];
  __syncthreads();
  {
    const int row = t >> 5;
    const int d0 = (t & 31) * 2;
    float mstar = sml[0][0][row];
#pragma unroll
    for (int ww = 1; ww < 8; ++ww) mstar = fmaxf(mstar, sml[0][ww][row]);
    float lstar = 0.f, o0 = 0.f, o1 = 0.f;
#pragma unroll
    for (int ww = 0; ww < 8; ++ww) {
      const float f = exp2f(sml[0][ww][row] - mstar);
      lstar += sml[1][ww][row] * f;
      const float2 a2 = *(const float2*)&sacc[ww][row][d0];
      o0 += a2.x * f;
      o1 += a2.y * f;
    }
    const float rl = 1.0f / lstar;
    float2 o; o.x = o0 * rl; o.y = o1 * rl;
    *(float2*)(out + ((size_t)batch * SS + q0 + 16 + row) * 64 + d0) = o;
  }
}

extern "C" void kernel_launch(void* const* d_in, const int* in_sizes, int n_in,
                              void* d_out, int out_size, void* d_ws, size_t ws_size,
                              hipStream_t stream) {
  const float* x  = (const float*)d_in[0];
  const float* Wq = (const float*)d_in[1];
  const float* Wk = (const float*)d_in[2];
  const float* Wv = (const float*)d_in[3];
  float* outp = (float*)d_out;

  unsigned short* qb = (unsigned short*)d_ws;           // 1 MB
  unsigned short* kb = qb + (size_t)BS * 64;            // 1 MB
  unsigned short* vt = kb + (size_t)BS * 64;            // 1 MB
  unsigned short* wt = vt + (size_t)BS * 64;            // 384 KB

  wt_prep<<<48, 256, 0, stream>>>(Wq, Wk, Wv, wt);
  qkv_mfma<<<BS / 32, 512, 0, stream>>>(x, wt, qb, kb, vt);
  attn_mfma<<<256, 512, 0, stream>>>(qb, kb, vt, outp);
}